// Round 13
// baseline (4349.435 us; speedup 1.0000x reference)
//
#include <hip/hip_runtime.h>
#include <cstdint>
#include <cstddef>

// Problem constants
#define Bb   256
#define Tt   512
#define Ii   300
#define Hh   128
#define G4   512      // 4*H
#define KP   320      // K padded to multiple of 32 for MFMA
#define KPA  328      // Axl row stride: 164 words = 4 mod 32 (near-floor b128 bank rounds)
#define CH   16       // steps per produced chunk
#define NCH  (Tt/CH)  // 32 chunks

typedef _Float16 h2v   __attribute__((ext_vector_type(2)));
typedef _Float16 half8 __attribute__((ext_vector_type(8)));
typedef float    f32x4 __attribute__((ext_vector_type(4)));

static __device__ __forceinline__ h2v as_h2(unsigned int u){ union{unsigned int u; h2v h;} c; c.u=u; return c.h; }
static __device__ __forceinline__ unsigned int as_u32(h2v h){ union{unsigned int u; h2v h;} c; c.h=h; return c.u; }

#if __has_builtin(__builtin_amdgcn_fdot2)
#define FDOT2(a,b,c) __builtin_amdgcn_fdot2((a),(b),(c),false)
#else
static __device__ __forceinline__ float FDOT2(h2v a, h2v b, float c){
  return c + (float)a[0]*(float)b[0] + (float)a[1]*(float)b[1];
}
#endif

// LDS-only barrier: drains this wave's ds ops (cross-wave visibility), leaves
// global loads in flight (compiler inserts vmcnt at their use).
#define STEP_BARRIER() do {                                    \
    asm volatile("" ::: "memory");                             \
    asm volatile("s_waitcnt lgkmcnt(0)" ::: "memory");         \
    __builtin_amdgcn_s_barrier();                              \
    asm volatile("" ::: "memory");                             \
  } while(0)

// ---------------- conversion: W_ih -> f16 padded (rows PERMUTED pr=d*4+g), Whh packed, bias sum ---
__global__ __launch_bounds__(256) void conv_small(const float* __restrict__ Wih, const float* __restrict__ Whh,
      const float* __restrict__ bih, const float* __restrict__ bhh,
      unsigned int* __restrict__ W16, unsigned int* __restrict__ Whh2, float* __restrict__ bias){
  int idx = blockIdx.x*256 + threadIdx.x;
  if (idx < G4*160){
    int pr = idx/160, kk2 = idx - pr*160, kk = kk2*2;
    int gc = (pr&3)*128 + (pr>>2);
    const float* wr = Wih + (size_t)gc*Ii;
    float v0 = (kk   < Ii) ? wr[kk]   : 0.f;
    float v1 = (kk+1 < Ii) ? wr[kk+1] : 0.f;
    h2v h; h[0]=(_Float16)v0; h[1]=(_Float16)v1;
    W16[idx] = as_u32(h);
  } else if (idx < G4*160 + G4*64){
    int t = idx - G4*160; int pr = t>>6, kk = t&63;
    int gc = (pr&3)*128 + (pr>>2);
    float v0 = Whh[gc*Hh + kk*2], v1 = Whh[gc*Hh + kk*2 + 1];
    h2v h; h[0]=(_Float16)v0; h[1]=(_Float16)v1;
    Whh2[t] = as_u32(h);
  } else if (idx < G4*160 + G4*64 + G4){
    int pr = idx - (G4*160 + G4*64);
    int gc = (pr&3)*128 + (pr>>2);
    bias[pr] = bih[gc] + bhh[gc];
  }
}

// ---------------- fused: recurrence (waves 0-7, R1 verbatim) + pipelined xg producer (waves 8-15) --
// All producer state in NAMED scalar registers via macros — no address-taken arrays,
// nothing can spill to scratch (round-12's 11.5 GB scratch bug, rule #20).
__global__ __launch_bounds__(1024,1) void lstm_fused(const float* __restrict__ x,
     const _Float16* __restrict__ Wih16, const float* __restrict__ bias,
     const unsigned int* __restrict__ Whh2,
     const float* __restrict__ fcw, const float* __restrict__ fcb, float* __restrict__ out){
  int tid = threadIdx.x;           // 0..1023
  int b = blockIdx.x;

  __shared__ float ring[2][CH*G4];                      // 64 KB, xg chunks (f32, permuted gates)
  __shared__ __align__(16) _Float16 Axl[CH][KPA];       // 10.25 KB, x chunk f16 (padded stride)
  __shared__ __align__(16) unsigned short hsh[2][128];
  __shared__ float red[128];

  // ---- consumer state (waves 0-7) ----
  int d = tid >> 2, g = tid & 3;
  int b0 = g & 1, b1 = (g >> 1) & 1;
  float km = (g == 2) ? 2.f : 1.f;   // tanh(a) = 2*sigmoid(2a)-1
  h2v w[64];
  float creg = 0.f, hreg = 0.f;

  // ---- producer state (waves 8-15), all named regs ----
  int pw  = (tid >> 6) - 8;          // producer wave id 0..7 (valid when tid>=512)
  int pln = tid & 63;
  int pq = pln >> 4, pmr = pln & 15;
  f32x4 acc0 = (f32x4){0,0,0,0}, acc1 = (f32x4){0,0,0,0};
  f32x4 acc2 = (f32x4){0,0,0,0}, acc3 = (f32x4){0,0,0,0};
  float bias0 = 0.f, bias1 = 0.f, bias2 = 0.f, bias3 = 0.f;
  half8 bfA0{}, bfA1{}, bfA2{}, bfA3{};   // W-fragment double buffer (named)
  half8 bfB0{}, bfB1{}, bfB2{}, bfB3{};
  float4 xs0{}, xs1{}, xs2{}, xs3{};      // staged x loads (named)
  // producer item indices (constant per thread)
  int id0 = tid - 512;                    // 0..511  (always < 640)
  int r0 = id0/40, k0 = id0 - r0*40;
  int id1 = tid;                          // 512..1023 (< 640 only for tid<640)
  int r1 = id1/40, k1 = id1 - r1*40;
  bool it1 = (id1 < CH*40);

#define LOAD_FRAGS(kt, B0, B1, B2, B3) {                                          \
    const _Float16* wb_ = Wih16 + (size_t)(pw*64 + pmr)*KP + (kt)*32 + pq*8;      \
    B0 = *(const half8*)(wb_);                                                    \
    B1 = *(const half8*)(wb_ + (size_t)16*KP);                                    \
    B2 = *(const half8*)(wb_ + (size_t)32*KP);                                    \
    B3 = *(const half8*)(wb_ + (size_t)48*KP);                                    \
  }
#define MFMA_KT(kt, B0, B1, B2, B3) {                                             \
    half8 af_ = *(const half8*)&Axl[pmr][(kt)*32 + pq*8];                         \
    acc0 = __builtin_amdgcn_mfma_f32_16x16x32_f16(af_, B0, acc0, 0,0,0);          \
    acc1 = __builtin_amdgcn_mfma_f32_16x16x32_f16(af_, B1, acc1, 0,0,0);          \
    acc2 = __builtin_amdgcn_mfma_f32_16x16x32_f16(af_, B2, acc2, 0,0,0);          \
    acc3 = __builtin_amdgcn_mfma_f32_16x16x32_f16(af_, B3, acc3, 0,0,0);          \
  }
#define STAGE_X(c) {                                                              \
    const float* s0_ = x + (size_t)(b*Tt + (c)*CH + r0)*Ii + k0*8;                \
    if (k0 < 37){ xs0 = *(const float4*)s0_; xs1 = *(const float4*)(s0_+4); }     \
    else if (k0 == 37){ xs0 = *(const float4*)s0_; xs1 = (float4){0,0,0,0}; }     \
    else { xs0 = (float4){0,0,0,0}; xs1 = (float4){0,0,0,0}; }                    \
    if (it1){                                                                     \
      const float* s1_ = x + (size_t)(b*Tt + (c)*CH + r1)*Ii + k1*8;              \
      if (k1 < 37){ xs2 = *(const float4*)s1_; xs3 = *(const float4*)(s1_+4); }   \
      else if (k1 == 37){ xs2 = *(const float4*)s1_; xs3 = (float4){0,0,0,0}; }   \
      else { xs2 = (float4){0,0,0,0}; xs3 = (float4){0,0,0,0}; }                  \
    }                                                                             \
  }
#define AXL_WRITE() {                                                             \
    union{ _Float16 h[8]; uint4 u; } o_;                                          \
    o_.h[0]=(_Float16)xs0.x; o_.h[1]=(_Float16)xs0.y;                             \
    o_.h[2]=(_Float16)xs0.z; o_.h[3]=(_Float16)xs0.w;                             \
    o_.h[4]=(_Float16)xs1.x; o_.h[5]=(_Float16)xs1.y;                             \
    o_.h[6]=(_Float16)xs1.z; o_.h[7]=(_Float16)xs1.w;                             \
    *(uint4*)&Axl[r0][k0*8] = o_.u;                                               \
    if (it1){                                                                     \
      o_.h[0]=(_Float16)xs2.x; o_.h[1]=(_Float16)xs2.y;                           \
      o_.h[2]=(_Float16)xs2.z; o_.h[3]=(_Float16)xs2.w;                           \
      o_.h[4]=(_Float16)xs3.x; o_.h[5]=(_Float16)xs3.y;                           \
      o_.h[6]=(_Float16)xs3.z; o_.h[7]=(_Float16)xs3.w;                           \
      *(uint4*)&Axl[r1][k1*8] = o_.u;                                             \
    }                                                                             \
  }
#define WRITE_RING(bw) {                                                          \
    float* rg_ = &ring[bw][0];                                                    \
    int g0_ = pw*64 + pmr;                                                        \
    rg_[(pq*4+0)*G4 + g0_   ] = acc0[0] + bias0;                                  \
    rg_[(pq*4+1)*G4 + g0_   ] = acc0[1] + bias0;                                  \
    rg_[(pq*4+2)*G4 + g0_   ] = acc0[2] + bias0;                                  \
    rg_[(pq*4+3)*G4 + g0_   ] = acc0[3] + bias0;                                  \
    rg_[(pq*4+0)*G4 + g0_+16] = acc1[0] + bias1;                                  \
    rg_[(pq*4+1)*G4 + g0_+16] = acc1[1] + bias1;                                  \
    rg_[(pq*4+2)*G4 + g0_+16] = acc1[2] + bias1;                                  \
    rg_[(pq*4+3)*G4 + g0_+16] = acc1[3] + bias1;                                  \
    rg_[(pq*4+0)*G4 + g0_+32] = acc2[0] + bias2;                                  \
    rg_[(pq*4+1)*G4 + g0_+32] = acc2[1] + bias2;                                  \
    rg_[(pq*4+2)*G4 + g0_+32] = acc2[2] + bias2;                                  \
    rg_[(pq*4+3)*G4 + g0_+32] = acc2[3] + bias2;                                  \
    rg_[(pq*4+0)*G4 + g0_+48] = acc3[0] + bias3;                                  \
    rg_[(pq*4+1)*G4 + g0_+48] = acc3[1] + bias3;                                  \
    rg_[(pq*4+2)*G4 + g0_+48] = acc3[2] + bias3;                                  \
    rg_[(pq*4+3)*G4 + g0_+48] = acc3[3] + bias3;                                  \
    acc0 = (f32x4){0,0,0,0}; acc1 = (f32x4){0,0,0,0};                             \
    acc2 = (f32x4){0,0,0,0}; acc3 = (f32x4){0,0,0,0};                             \
  }

  if (tid < 512){
    #pragma unroll
    for (int kk=0; kk<64; ++kk) w[kk] = as_h2(Whh2[tid*64 + kk]);
    if (tid < 128) hsh[0][tid] = 0;
  } else {
    bias0 = bias[pw*64 + pmr];
    bias1 = bias[pw*64 + 16 + pmr];
    bias2 = bias[pw*64 + 32 + pmr];
    bias3 = bias[pw*64 + 48 + pmr];
    STAGE_X(0);
    AXL_WRITE();
  }
  __syncthreads();                       // Axl(chunk0) + hsh0 visible
  if (tid >= 512){
    // chunk 0 straight-line (one-time exposed latency)
    #pragma unroll
    for (int kt=0; kt<KP/32; ++kt){
      LOAD_FRAGS(kt, bfA0, bfA1, bfA2, bfA3);
      MFMA_KT(kt, bfA0, bfA1, bfA2, bfA3);
    }
    WRITE_RING(0);
    STAGE_X(1);                          // chunk 1 x loads start flying
  }
  __syncthreads();                       // ring[0] visible to consumers

  for (int t=0; t<Tt; ++t){
    if (tid < 512){
      // ---------- consumer: R1 verbatim, xc from ring ----------
      float xc = ring[(t>>4)&1][(t&15)*G4 + tid];
      const uint4* hv = (const uint4*)hsh[t & 1];
      float a0 = xc, a1 = 0.f, a2 = 0.f, a3 = 0.f;
      #pragma unroll
      for (int kq=0; kq<8; ++kq){
        uint4 hq0 = hv[kq*2], hq1 = hv[kq*2+1];
        a0 = FDOT2(as_h2(hq0.x), w[kq*8+0], a0); a1 = FDOT2(as_h2(hq0.y), w[kq*8+1], a1);
        a2 = FDOT2(as_h2(hq0.z), w[kq*8+2], a2); a3 = FDOT2(as_h2(hq0.w), w[kq*8+3], a3);
        a0 = FDOT2(as_h2(hq1.x), w[kq*8+4], a0); a1 = FDOT2(as_h2(hq1.y), w[kq*8+5], a1);
        a2 = FDOT2(as_h2(hq1.z), w[kq*8+6], a2); a3 = FDOT2(as_h2(hq1.w), w[kq*8+7], a3);
      }
      float a = (a0 + a1) + (a2 + a3);
      float s_  = 1.f/(1.f + __expf(-km*a));
      float act = (g == 2) ? (2.f*s_ - 1.f) : s_;
      float u1 = __shfl_xor(act, 1);
      float u2 = __shfl_xor(act, 2);
      float u3 = __shfl_xor(act, 3);
      float pl = b0 ? u1  : act;
      float ph = b0 ? u3  : u2;
      float ql = b0 ? act : u1;
      float qh = b0 ? u2  : u3;
      float i_ = b1 ? ph : pl;
      float f_ = b1 ? qh : ql;
      float g_ = b1 ? pl : ph;
      float o_ = b1 ? ql : qh;
      creg = f_*creg + i_*g_;
      float ec = __expf(2.f*creg); float tc = 1.f - 2.f/(ec+1.f);
      hreg = o_*tc;
      if (g == 0){
        union{ _Float16 f; unsigned short s; } cv; cv.f = (_Float16)hreg;
        hsh[(t+1) & 1][d] = cv.s;
      }
    } else if (t < Tt - CH){
      // ---------- producer: build chunk c+1 = (t>>4)+1, software-pipelined ----------
      int s = t & 15;
      int c1 = (t >> 4) + 1;
      if (s == 0){
        AXL_WRITE();                               // x(c+1) regs -> Axl
      } else if (s <= 11){
        if (s & 1){
          if (s <= 10) LOAD_FRAGS(s-1, bfB0, bfB1, bfB2, bfB3);
          if (s >= 2)  MFMA_KT(s-2, bfA0, bfA1, bfA2, bfA3);
        } else {
          if (s <= 10) LOAD_FRAGS(s-1, bfA0, bfA1, bfA2, bfA3);
          MFMA_KT(s-2, bfB0, bfB1, bfB2, bfB3);
        }
      } else if (s == 12){
        WRITE_RING(c1 & 1);
      } else if (s == 13){
        if (c1 + 1 < NCH) STAGE_X(c1 + 1);         // next x chunk starts flying
      }
      // s==14,15: idle
    }
    STEP_BARRIER();
  }

  // fused FC: out[b] = sum_d h_d * fcw[d] + fcb
  if (tid < 512 && g == 0) red[d] = hreg * fcw[d];
  __syncthreads();
  #pragma unroll
  for (int s2=64; s2>=1; s2>>=1){
    if (tid < s2) red[tid] += red[tid+s2];
    __syncthreads();
  }
  if (tid == 0) out[b] = red[0] + fcb[0];
}

extern "C" void kernel_launch(void* const* d_in, const int* in_sizes, int n_in,
                              void* d_out, int out_size, void* d_ws, size_t ws_size,
                              hipStream_t stream){
  const float* x   = (const float*)d_in[0];
  const float* Wih = (const float*)d_in[1];
  const float* Whh = (const float*)d_in[2];
  const float* bih = (const float*)d_in[3];
  const float* bhh = (const float*)d_in[4];
  const float* fcw = (const float*)d_in[5];
  const float* fcb = (const float*)d_in[6];
  float* out = (float*)d_out;
  char* ws = (char*)d_ws;

  // ws layout (bytes) — only the small converted weights are needed:
  //   W16  : 83,886,080 .. +327,680     (512*320 f16, rows permuted d*4+g)
  //   Whh2 : 84,213,760 .. +131,072     (512*64 half2, rows permuted d*4+g)
  //   bias : 84,344,832 .. +2,048       (512 f32, permuted d*4+g)
  unsigned int* W16   = (unsigned int*)(ws + 83886080);
  unsigned int* Whh2w = (unsigned int*)(ws + 84213760);
  float*        bias  = (float*)      (ws + 84344832);

  hipLaunchKernelGGL(conv_small, dim3(450), dim3(256), 0, stream, Wih, Whh, bih, bhh, W16, Whh2w, bias);
  hipLaunchKernelGGL(lstm_fused, dim3(256), dim3(1024), 0, stream,
                     x, (const _Float16*)W16, bias, Whh2w, fcw, fcb, out);
}

// Round 14
// 763.083 us; speedup vs baseline: 5.6998x; 5.6998x over previous
//
#include <hip/hip_runtime.h>
#include <cstdint>
#include <cstddef>

// Problem constants
#define Bb   256
#define Tt   512
#define Ii   300
#define Hh   128
#define G4   512      // 4*H
#define KP   320      // K padded to multiple of 32 for MFMA
#define KPA  328      // Axl row stride: 164 words = 4 mod 32 -> 8-round (floor) b128 reads
#define CH   16       // steps per produced chunk
#define NCH  (Tt/CH)  // 32 chunks

typedef _Float16 h2v   __attribute__((ext_vector_type(2)));
typedef _Float16 half8 __attribute__((ext_vector_type(8)));
typedef float    f32x4 __attribute__((ext_vector_type(4)));

static __device__ __forceinline__ h2v as_h2(unsigned int u){ union{unsigned int u; h2v h;} c; c.u=u; return c.h; }
static __device__ __forceinline__ unsigned int as_u32(h2v h){ union{unsigned int u; h2v h;} c; c.h=h; return c.u; }

#if __has_builtin(__builtin_amdgcn_fdot2)
#define FDOT2(a,b,c) __builtin_amdgcn_fdot2((a),(b),(c),false)
#else
static __device__ __forceinline__ float FDOT2(h2v a, h2v b, float c){
  return c + (float)a[0]*(float)b[0] + (float)a[1]*(float)b[1];
}
#endif

// LDS-only step barrier: drains this wave's ds ops (cross-wave LDS visibility),
// leaves global loads in flight (wave-private; compiler inserts vmcnt at use).
// Replaces __syncthreads' vmcnt(0) drain, which serialized producer load latency
// onto every step (the m97 barrier-drain stall).
#define STEP_BARRIER() do {                                    \
    asm volatile("" ::: "memory");                             \
    asm volatile("s_waitcnt lgkmcnt(0)" ::: "memory");         \
    __builtin_amdgcn_s_barrier();                              \
    asm volatile("" ::: "memory");                             \
  } while(0)

// ---------------- conversion: W_ih -> f16 padded (rows PERMUTED pr=d*4+g), Whh packed, bias sum ---
// Row permutation: output row pr corresponds to original gate row gc = (pr&3)*128 + (pr>>2).
__global__ __launch_bounds__(256) void conv_small(const float* __restrict__ Wih, const float* __restrict__ Whh,
      const float* __restrict__ bih, const float* __restrict__ bhh,
      unsigned int* __restrict__ W16, unsigned int* __restrict__ Whh2, float* __restrict__ bias){
  int idx = blockIdx.x*256 + threadIdx.x;
  if (idx < G4*160){
    int pr = idx/160, kk2 = idx - pr*160, kk = kk2*2;
    int gc = (pr&3)*128 + (pr>>2);
    const float* wr = Wih + (size_t)gc*Ii;
    float v0 = (kk   < Ii) ? wr[kk]   : 0.f;
    float v1 = (kk+1 < Ii) ? wr[kk+1] : 0.f;
    h2v h; h[0]=(_Float16)v0; h[1]=(_Float16)v1;
    W16[idx] = as_u32(h);
  } else if (idx < G4*160 + G4*64){
    int t = idx - G4*160; int pr = t>>6, kk = t&63;
    int gc = (pr&3)*128 + (pr>>2);
    float v0 = Whh[gc*Hh + kk*2], v1 = Whh[gc*Hh + kk*2 + 1];
    h2v h; h[0]=(_Float16)v0; h[1]=(_Float16)v1;
    Whh2[t] = as_u32(h);
  } else if (idx < G4*160 + G4*64 + G4){
    int pr = idx - (G4*160 + G4*64);
    int gc = (pr&3)*128 + (pr>>2);
    bias[pr] = bih[gc] + bhh[gc];
  }
}

// ---------------- fused: recurrence (waves 0-7, R1 verbatim) + xg producer (waves 8-15) ----------
// EXACTLY the round-11 structure (proved spill-free: FETCH 78MB / WRITE 8KB) with only
// two defect fixes: (1) Axl stride 328 (bank-round floor), (2) LDS-only step barrier.
// Producer state is transient-per-phase (frags loaded & consumed in the same phase) —
// only acc[4]+biasv[4] live across barriers, fitting the 128-reg/wave budget
// alongside the consumer's w[64] (which lives in the AGPR half of the unified file).
__global__ __launch_bounds__(1024,1) void lstm_fused(const float* __restrict__ x,
     const _Float16* __restrict__ Wih16, const float* __restrict__ bias,
     const unsigned int* __restrict__ Whh2,
     const float* __restrict__ fcw, const float* __restrict__ fcb, float* __restrict__ out){
  int tid = threadIdx.x;           // 0..1023
  int b = blockIdx.x;

  __shared__ float ring[2][CH*G4];                      // 64 KB, xg chunks (f32, permuted gates)
  __shared__ __align__(16) _Float16 Axl[CH][KPA];       // 10.25 KB, x chunk f16 (padded stride)
  __shared__ __align__(16) unsigned short hsh[2][128];
  __shared__ float red[128];

  // ---- consumer state (waves 0-7) ----
  int d = tid >> 2, g = tid & 3;
  int b0 = g & 1, b1 = (g >> 1) & 1;
  float km = (g == 2) ? 2.f : 1.f;   // tanh(a) = 2*sigmoid(2a)-1
  h2v w[64];
  float creg = 0.f, hreg = 0.f;

  // ---- producer state (waves 8-15) ----
  int pw  = (tid >> 6) - 8;          // producer wave id 0..7 (valid when tid>=512)
  int pln = tid & 63;
  int pq = pln >> 4, pmr = pln & 15;
  f32x4 acc[4];
  float biasv[4];
  #pragma unroll
  for (int j=0;j<4;j++) acc[j] = (f32x4){0.f,0.f,0.f,0.f};

  // stage x chunk c into Axl as f16 (640 uint4 items; 512 producer threads, 2 items each)
  auto stage_x = [&](int c){
    #pragma unroll
    for (int i=0;i<2;i++){
      int idx = (tid - 512) + i*512;
      if (idx < CH*40){
        int r = idx/40, k = idx - r*40;
        union{ _Float16 h[8]; uint4 u; } o;
        const float* src = x + (size_t)(b*Tt + c*CH + r)*Ii + k*8;
        if (k < 37){
          float4 a4 = *(const float4*)src;
          float4 c4 = *(const float4*)(src+4);
          o.h[0]=(_Float16)a4.x; o.h[1]=(_Float16)a4.y; o.h[2]=(_Float16)a4.z; o.h[3]=(_Float16)a4.w;
          o.h[4]=(_Float16)c4.x; o.h[5]=(_Float16)c4.y; o.h[6]=(_Float16)c4.z; o.h[7]=(_Float16)c4.w;
        } else if (k == 37){
          float4 a4 = *(const float4*)src;
          o.h[0]=(_Float16)a4.x; o.h[1]=(_Float16)a4.y; o.h[2]=(_Float16)a4.z; o.h[3]=(_Float16)a4.w;
          o.h[4]=(_Float16)0.f; o.h[5]=(_Float16)0.f; o.h[6]=(_Float16)0.f; o.h[7]=(_Float16)0.f;
        } else {
          o.u = (uint4){0u,0u,0u,0u};
        }
        *(uint4*)&Axl[r][k*8] = o.u;
      }
    }
  };
  // one K-subtile: 4 B-frag loads (L2) + 1 A ds_read + 4 MFMA (transient frags)
  auto produce_kt = [&](int kt){
    const _Float16* wb = Wih16 + (size_t)(pw*64 + pmr)*KP + kt*32 + pq*8;
    half8 bf0 = *(const half8*)(wb);
    half8 bf1 = *(const half8*)(wb + (size_t)16*KP);
    half8 bf2 = *(const half8*)(wb + (size_t)32*KP);
    half8 bf3 = *(const half8*)(wb + (size_t)48*KP);
    half8 af  = *(const half8*)&Axl[pmr][kt*32 + pq*8];
    acc[0] = __builtin_amdgcn_mfma_f32_16x16x32_f16(af, bf0, acc[0], 0,0,0);
    acc[1] = __builtin_amdgcn_mfma_f32_16x16x32_f16(af, bf1, acc[1], 0,0,0);
    acc[2] = __builtin_amdgcn_mfma_f32_16x16x32_f16(af, bf2, acc[2], 0,0,0);
    acc[3] = __builtin_amdgcn_mfma_f32_16x16x32_f16(af, bf3, acc[3], 0,0,0);
  };
  auto write_ring = [&](int bw){
    #pragma unroll
    for (int j=0;j<4;j++){
      int gate = pw*64 + j*16 + pmr;
      #pragma unroll
      for (int rg=0;rg<4;rg++)
        ring[bw][(pq*4+rg)*G4 + gate] = acc[j][rg] + biasv[j];
      acc[j] = (f32x4){0.f,0.f,0.f,0.f};
    }
  };

  if (tid < 512){
    #pragma unroll
    for (int kk=0; kk<64; ++kk) w[kk] = as_h2(Whh2[tid*64 + kk]);
    if (tid < 128) hsh[0][tid] = 0;
  } else {
    #pragma unroll
    for (int j=0;j<4;j++) biasv[j] = bias[pw*64 + j*16 + pmr];
    stage_x(0);
  }
  __syncthreads();                       // Axl(chunk0) visible to producer waves
  if (tid >= 512){
    #pragma unroll
    for (int kt=0; kt<KP/32; ++kt) produce_kt(kt);
    write_ring(0);                       // chunk 0 -> ring[0]
  }
  __syncthreads();                       // ring[0] visible to consumers

  for (int t=0; t<Tt; ++t){
    if (tid < 512){
      // ---------- consumer: R1 verbatim, xc from ring ----------
      float xc = ring[(t>>4)&1][(t&15)*G4 + tid];
      const uint4* hv = (const uint4*)hsh[t & 1];
      float a0 = xc, a1 = 0.f, a2 = 0.f, a3 = 0.f;
      #pragma unroll
      for (int kq=0; kq<8; ++kq){
        uint4 hq0 = hv[kq*2], hq1 = hv[kq*2+1];
        a0 = FDOT2(as_h2(hq0.x), w[kq*8+0], a0); a1 = FDOT2(as_h2(hq0.y), w[kq*8+1], a1);
        a2 = FDOT2(as_h2(hq0.z), w[kq*8+2], a2); a3 = FDOT2(as_h2(hq0.w), w[kq*8+3], a3);
        a0 = FDOT2(as_h2(hq1.x), w[kq*8+4], a0); a1 = FDOT2(as_h2(hq1.y), w[kq*8+5], a1);
        a2 = FDOT2(as_h2(hq1.z), w[kq*8+6], a2); a3 = FDOT2(as_h2(hq1.w), w[kq*8+7], a3);
      }
      float a = (a0 + a1) + (a2 + a3);
      float s_  = 1.f/(1.f + __expf(-km*a));
      float act = (g == 2) ? (2.f*s_ - 1.f) : s_;
      float u1 = __shfl_xor(act, 1);
      float u2 = __shfl_xor(act, 2);
      float u3 = __shfl_xor(act, 3);
      float pl = b0 ? u1  : act;
      float ph = b0 ? u3  : u2;
      float ql = b0 ? act : u1;
      float qh = b0 ? u2  : u3;
      float i_ = b1 ? ph : pl;
      float f_ = b1 ? qh : ql;
      float g_ = b1 ? pl : ph;
      float o_ = b1 ? ql : qh;
      creg = f_*creg + i_*g_;
      float ec = __expf(2.f*creg); float tc = 1.f - 2.f/(ec+1.f);
      hreg = o_*tc;
      if (g == 0){
        union{ _Float16 f; unsigned short s; } cv; cv.f = (_Float16)hreg;
        hsh[(t+1) & 1][d] = cv.s;
      }
    } else if (t < Tt - CH){
      // ---------- producer: build chunk (t>>4)+1 into ring[(c+1)&1] ----------
      int s = t & 15;
      if (s == 0)                stage_x((t>>4) + 1);
      else if (s >= 2 && s < 12) produce_kt(s - 2);
      else if (s == 12)          write_ring(((t>>4) + 1) & 1);
    }
    STEP_BARRIER();
  }

  // fused FC: out[b] = sum_d h_d * fcw[d] + fcb
  if (tid < 512 && g == 0) red[d] = hreg * fcw[d];
  __syncthreads();
  #pragma unroll
  for (int s2=64; s2>=1; s2>>=1){
    if (tid < s2) red[tid] += red[tid+s2];
    __syncthreads();
  }
  if (tid == 0) out[b] = red[0] + fcb[0];
}

extern "C" void kernel_launch(void* const* d_in, const int* in_sizes, int n_in,
                              void* d_out, int out_size, void* d_ws, size_t ws_size,
                              hipStream_t stream){
  const float* x   = (const float*)d_in[0];
  const float* Wih = (const float*)d_in[1];
  const float* Whh = (const float*)d_in[2];
  const float* bih = (const float*)d_in[3];
  const float* bhh = (const float*)d_in[4];
  const float* fcw = (const float*)d_in[5];
  const float* fcb = (const float*)d_in[6];
  float* out = (float*)d_out;
  char* ws = (char*)d_ws;

  // ws layout (bytes) — only the small converted weights are needed:
  //   W16  : 83,886,080 .. +327,680     (512*320 f16, rows permuted d*4+g)
  //   Whh2 : 84,213,760 .. +131,072     (512*64 half2, rows permuted d*4+g)
  //   bias : 84,344,832 .. +2,048       (512 f32, permuted d*4+g)
  unsigned int* W16   = (unsigned int*)(ws + 83886080);
  unsigned int* Whh2w = (unsigned int*)(ws + 84213760);
  float*        bias  = (float*)      (ws + 84344832);

  hipLaunchKernelGGL(conv_small, dim3(450), dim3(256), 0, stream, Wih, Whh, bih, bhh, W16, Whh2w, bias);
  hipLaunchKernelGGL(lstm_fused, dim3(256), dim3(1024), 0, stream,
                     x, (const _Float16*)W16, bias, Whh2w, fcw, fcb, out);
}